// Round 15
// baseline (90.248 us; speedup 1.0000x reference)
//
#include <hip/hip_runtime.h>
#include <hip/hip_bf16.h>

// TextEncoder: segment-mean pool -> relu(x@W1+b1) -> relu(h@W2+b2) -> LayerNorm
// R15 = R11 + ATTRIBUTION PROBE #2: prep and gemm2_ln each launched TWICE
// (idempotent, deterministic); gemm1 single. R15 - 55.9 = prep + gemm2_ln
// (warm). With R14's gemm1=15.6us this completes the decomposition and pins
// the unexplained ~17us (fixed overhead vs underestimated components).
//
// Padding: W1T=[512][768] (rows>=500 zero) -> h1 pad cols = relu(0)=0;
// W2T=[320][512] (k>=500, n>=300 zero) -> pad out cols = 0, excluded from LN.

#define N_  64
#define L_  514
#define D_  768
#define W_  256
#define H1_ 500
#define H1P 512
#define H2_ 300
#define H2P 320
#define LN_EPS 1e-5f
#define M_  (N_ * W_)   // 16384

typedef __bf16 bf16x8 __attribute__((ext_vector_type(8)));
typedef float  f32x4  __attribute__((ext_vector_type(4)));

__device__ __forceinline__ void load_lds16(const void* g, void* l) {
    __builtin_amdgcn_global_load_lds(
        (const __attribute__((address_space(1))) void*)g,
        (__attribute__((address_space(3))) void*)l, 16, 0, 0);
}

// ------------------------------------------------------------------ prep ---
#define CONV1_ELEMS (H1P * D_)     // 393216
#define CONV2_ELEMS (H2P * H1P)    // 163840
#define CONV1_B ((CONV1_ELEMS + 191) / 192)   // 2048
#define CONV2_B ((CONV2_ELEMS + 191) / 192)   // 854

__global__ __launch_bounds__(192) void prep_kernel(
    const float* __restrict__ texts, const int* __restrict__ wstart,
    const int* __restrict__ wend, const int* __restrict__ wlen,
    const float* __restrict__ W1, const float* __restrict__ W2,
    __hip_bfloat16* __restrict__ pooled, __hip_bfloat16* __restrict__ W1T,
    __hip_bfloat16* __restrict__ W2T)
{
    int b = blockIdx.x;
    if (b < M_) {
        int n = b >> 8;
        int w = b & (W_ - 1);
        int s = wstart[b], e = wend[b];
        bool live = (w < wlen[n]);
        int d = threadIdx.x * 4;
        float4 acc = make_float4(0.f, 0.f, 0.f, 0.f);
        if (live) {
            const float* base = texts + ((size_t)n * L_ + 1) * D_ + d;  // tok=texts[:,1:-1]
            for (int i = s; i < e; ++i) {
                float4 v = *reinterpret_cast<const float4*>(base + (size_t)i * D_);
                acc.x += v.x; acc.y += v.y; acc.z += v.z; acc.w += v.w;
            }
            float inv = 1.0f / (float)max(e - s, 1);
            acc.x *= inv; acc.y *= inv; acc.z *= inv; acc.w *= inv;
        }
        union { __hip_bfloat16 h[4]; uint2 u; } o;
        o.h[0] = __float2bfloat16(acc.x); o.h[1] = __float2bfloat16(acc.y);
        o.h[2] = __float2bfloat16(acc.z); o.h[3] = __float2bfloat16(acc.w);
        *reinterpret_cast<uint2*>(pooled + (size_t)b * D_ + d) = o.u;
    } else if (b < M_ + CONV1_B) {
        int t = (b - M_) * 192 + threadIdx.x;
        if (t < CONV1_ELEMS) {
            int n = t / D_, k = t - n * D_;
            float v = (n < H1_) ? W1[(size_t)k * H1_ + n] : 0.f;
            W1T[t] = __float2bfloat16(v);
        }
    } else {
        int t = (b - M_ - CONV1_B) * 192 + threadIdx.x;
        if (t < CONV2_ELEMS) {
            int n = t >> 9, k = t & (H1P - 1);
            float v = (n < H2_ && k < H1_) ? W2[(size_t)k * H2_ + n] : 0.f;
            W2T[t] = __float2bfloat16(v);
        }
    }
}

// --------------------------------------------------------- GEMM1 (MFMA) ----
// [R11 verbatim] BM=256, BN=128, BK=64; 8 waves (4x2); 12 K-steps; 3 bufs x
// 48KB; depth-2 counted vmcnt (6 loads/wave/stage -> vmcnt(6), tail 0).
__global__ __launch_bounds__(512, 1) void gemm1_kernel(
    const ushort* __restrict__ A, const ushort* __restrict__ B,
    const float* __restrict__ b1, ushort* __restrict__ h1)
{
    constexpr int BUFB = 49152;                 // 384 rows * 128 B
    __shared__ __align__(16) char bufs[3 * BUFB];   // 144 KB
    const int tid  = threadIdx.x;
    const int wave = tid >> 6, lane = tid & 63;
    const int wm = wave >> 1, wn = wave & 1;    // 4 x 2
    const int t256 = (blockIdx.x & 7) * 32 + (blockIdx.x >> 3);
    const int bm = (t256 >> 2) * 256, bn = (t256 & 3) * 128;
    const int lrow8 = lane >> 3, lslot8 = lane & 7;
    const int g = lane >> 4, fr = lane & 15;

    f32x4 acc[4][4] = {};

    auto stage = [&](int buf, int kt) {
        char* base = bufs + buf * BUFB;
        #pragma unroll
        for (int c0 = 0; c0 < 6; ++c0) {
            int c = wave + c0 * 8;              // 0..47
            int row; const ushort* src;
            if (c < 32) { row = c * 8 + lrow8;        src = A + (size_t)(bm + row) * D_; }
            else        { row = (c - 32) * 8 + lrow8; src = B + (size_t)(bn + row) * D_; }
            int sslot = lslot8 ^ (row & 7);
            load_lds16(src + kt + sslot * 8, base + c * 1024);
        }
    };

    auto compute = [&](int t) {
        const char* base = bufs + (t % 3) * BUFB;
        #pragma unroll
        for (int h = 0; h < 2; ++h) {
            bf16x8 af[4], bf[4];
            #pragma unroll
            for (int mi = 0; mi < 4; ++mi) {
                int r = wm * 64 + mi * 16 + fr;
                af[mi] = *(const bf16x8*)(base + r * 128 + ((((h << 2) + g) ^ (r & 7)) << 4));
            }
            #pragma unroll
            for (int ni = 0; ni < 4; ++ni) {
                int r = wn * 64 + ni * 16 + fr;
                bf[ni] = *(const bf16x8*)(base + 32768 + r * 128 + ((((h << 2) + g) ^ (r & 7)) << 4));
            }
            __builtin_amdgcn_s_setprio(1);
            #pragma unroll
            for (int mi = 0; mi < 4; ++mi)
                #pragma unroll
                for (int ni = 0; ni < 4; ++ni)
                    acc[mi][ni] = __builtin_amdgcn_mfma_f32_16x16x32_bf16(
                        af[mi], bf[ni], acc[mi][ni], 0, 0, 0);
            __builtin_amdgcn_s_setprio(0);
        }
    };

    stage(0, 0); stage(1, 64);
    for (int t = 0; t < 11; ++t) {
        asm volatile("s_waitcnt vmcnt(6)" ::: "memory");   // stage t complete
        __builtin_amdgcn_s_barrier();
        if (t + 2 < 12) stage((t + 2) % 3, (t + 2) * 64);
        compute(t);
    }
    asm volatile("s_waitcnt vmcnt(0)" ::: "memory");
    __builtin_amdgcn_s_barrier();
    compute(11);

    #pragma unroll
    for (int mi = 0; mi < 4; ++mi)
        #pragma unroll
        for (int ni = 0; ni < 4; ++ni) {
            int col = bn + wn * 64 + ni * 16 + fr;
            float bv = (col < H1_) ? b1[col] : 0.f;
            #pragma unroll
            for (int j = 0; j < 4; ++j) {
                int row = bm + wm * 64 + mi * 16 + g * 4 + j;
                float v = acc[mi][ni][j] + bv;
                ((__hip_bfloat16*)h1)[(size_t)row * H1P + col] =
                    __float2bfloat16(v > 0.f ? v : 0.f);
            }
        }
}

// ------------------------------------------- GEMM2 + bias + relu + LN ------
// [R6 verbatim] BM=64, BN=320 full-row, K=512; 8 waves (2x4); 4-buf counted
// vmcnt (6/3/0); LN fused in epilogue.
__global__ __launch_bounds__(512, 1) void gemm2_ln_kernel(
    const ushort* __restrict__ A, const ushort* __restrict__ B,
    const float* __restrict__ b2, const float* __restrict__ gamma,
    const float* __restrict__ beta, float* __restrict__ out)
{
    constexpr int BUFB = 24576;                 // (64+320) rows * 64 B
    __shared__ __align__(16) char bufs[4 * BUFB];   // 96 KB
    __shared__ float red[2][32][4][2];          // [wm][row][wn][sum|sq]
    const int tid  = threadIdx.x;
    const int wave = tid >> 6, lane = tid & 63;
    const int wm = wave >> 2, wn = wave & 3;    // 2 x 4
    const int bm = blockIdx.x * 64;
    const int lrow = lane >> 2, lslot = lane & 3;
    const int g = lane >> 4, fr = lane & 15;

    f32x4 acc[2][5] = {};

    auto stage = [&](int buf, int kt) {
        char* base = bufs + buf * BUFB;
        #pragma unroll
        for (int c0 = 0; c0 < 3; ++c0) {
            int c = wave + c0 * 8;              // 0..23
            int row; const ushort* src;
            if (c < 4) { row = c * 16 + lrow; src = A + (size_t)(bm + row) * H1P; }
            else       { row = (c - 4) * 16 + lrow; src = B + (size_t)row * H1P; }
            int sslot = lslot ^ ((row >> 1) & 3);
            load_lds16(src + kt + sslot * 8, base + c * 1024);
        }
    };

    auto compute = [&](int t) {
        const char* base = bufs + (t & 3) * BUFB;
        bf16x8 af[2], bf[5];
        #pragma unroll
        for (int mi = 0; mi < 2; ++mi) {
            int r = wm * 32 + mi * 16 + fr;
            af[mi] = *(const bf16x8*)(base + r * 64 + ((g ^ ((r >> 1) & 3)) << 4));
        }
        #pragma unroll
        for (int ni = 0; ni < 5; ++ni) {
            int r = wn * 80 + ni * 16 + fr;
            bf[ni] = *(const bf16x8*)(base + 4096 + r * 64 + ((g ^ ((r >> 1) & 3)) << 4));
        }
        __builtin_amdgcn_s_setprio(1);
        #pragma unroll
        for (int mi = 0; mi < 2; ++mi)
            #pragma unroll
            for (int ni = 0; ni < 5; ++ni)
                acc[mi][ni] = __builtin_amdgcn_mfma_f32_16x16x32_bf16(
                    af[mi], bf[ni], acc[mi][ni], 0, 0, 0);
        __builtin_amdgcn_s_setprio(0);
    };

    stage(0, 0); stage(1, 32); stage(2, 64);
    for (int t = 0; t < 14; ++t) {
        asm volatile("s_waitcnt vmcnt(6)" ::: "memory");
        __builtin_amdgcn_s_barrier();
        if (t + 3 < 16) stage((t + 3) & 3, (t + 3) * 32);
        compute(t);
    }
    asm volatile("s_waitcnt vmcnt(3)" ::: "memory");
    __builtin_amdgcn_s_barrier();
    compute(14);
    asm volatile("s_waitcnt vmcnt(0)" ::: "memory");
    __builtin_amdgcn_s_barrier();
    compute(15);

    float vals[2][5][4];
    float rsum[2][4] = {}, rsq[2][4] = {};
    #pragma unroll
    for (int ni = 0; ni < 5; ++ni) {
        int col = wn * 80 + ni * 16 + fr;
        float bv = (col < H2_) ? b2[col] : 0.f;
        #pragma unroll
        for (int mi = 0; mi < 2; ++mi)
            #pragma unroll
            for (int j = 0; j < 4; ++j) {
                float v = acc[mi][ni][j] + bv;
                v = v > 0.f ? v : 0.f;
                vals[mi][ni][j] = v;
                rsum[mi][j] += v;
                rsq[mi][j]  += v * v;
            }
    }
    #pragma unroll
    for (int off = 1; off < 16; off <<= 1)
        #pragma unroll
        for (int mi = 0; mi < 2; ++mi)
            #pragma unroll
            for (int j = 0; j < 4; ++j) {
                rsum[mi][j] += __shfl_xor(rsum[mi][j], off);
                rsq[mi][j]  += __shfl_xor(rsq[mi][j], off);
            }
    if (fr == 0) {
        #pragma unroll
        for (int mi = 0; mi < 2; ++mi)
            #pragma unroll
            for (int j = 0; j < 4; ++j) {
                int r32 = mi * 16 + g * 4 + j;
                red[wm][r32][wn][0] = rsum[mi][j];
                red[wm][r32][wn][1] = rsq[mi][j];
            }
    }
    __syncthreads();
    #pragma unroll
    for (int mi = 0; mi < 2; ++mi) {
        #pragma unroll
        for (int j = 0; j < 4; ++j) {
            int r32 = mi * 16 + g * 4 + j;
            float S  = red[wm][r32][0][0] + red[wm][r32][1][0]
                     + red[wm][r32][2][0] + red[wm][r32][3][0];
            float SQ = red[wm][r32][0][1] + red[wm][r32][1][1]
                     + red[wm][r32][2][1] + red[wm][r32][3][1];
            float mu   = S * (1.0f / H2_);
            float var  = SQ * (1.0f / H2_) - mu * mu;
            float rstd = rsqrtf(var + LN_EPS);
            int row = bm + wm * 32 + r32;
            #pragma unroll
            for (int ni = 0; ni < 5; ++ni) {
                int col = wn * 80 + ni * 16 + fr;
                if (col < H2_)
                    out[(size_t)row * H2_ + col] =
                        (vals[mi][ni][j] - mu) * rstd * gamma[col] + beta[col];
            }
        }
    }
}

// ----------------------------------------------------------------- launch ---
extern "C" void kernel_launch(void* const* d_in, const int* in_sizes, int n_in,
                              void* d_out, int out_size, void* d_ws, size_t ws_size,
                              hipStream_t stream)
{
    const float* texts  = (const float*)d_in[0];
    const int*   wstart = (const int*)  d_in[1];
    const int*   wend   = (const int*)  d_in[2];
    const int*   wlen   = (const int*)  d_in[3];
    const float* W1     = (const float*)d_in[4];
    const float* b1     = (const float*)d_in[5];
    const float* W2     = (const float*)d_in[6];
    const float* b2     = (const float*)d_in[7];
    const float* gamma  = (const float*)d_in[8];
    const float* beta   = (const float*)d_in[9];
    float* out = (float*)d_out;

    ushort* pooled = (ushort*)d_ws;                 // M x 768 bf16
    ushort* h1     = pooled + (size_t)M_ * D_;      // M x 512 bf16
    ushort* W1T    = h1 + (size_t)M_ * H1P;         // 512 x 768 bf16
    ushort* W2T    = W1T + (size_t)H1P * D_;        // 320 x 512 bf16

    // ATTRIBUTION PROBE #2 (R15): prep x2 and gemm2_ln x2 (both idempotent).
    // R15 - 55.9 = prep_warm + gemm2_warm.
    prep_kernel<<<M_ + CONV1_B + CONV2_B, 192, 0, stream>>>(
        texts, wstart, wend, wlen, W1, W2,
        (__hip_bfloat16*)pooled, (__hip_bfloat16*)W1T, (__hip_bfloat16*)W2T);
    prep_kernel<<<M_ + CONV1_B + CONV2_B, 192, 0, stream>>>(
        texts, wstart, wend, wlen, W1, W2,
        (__hip_bfloat16*)pooled, (__hip_bfloat16*)W1T, (__hip_bfloat16*)W2T);

    gemm1_kernel<<<256, 512, 0, stream>>>(pooled, W1T, b1, h1);

    gemm2_ln_kernel<<<M_ / 64, 512, 0, stream>>>(h1, W2T, b2, gamma, beta, out);
    gemm2_ln_kernel<<<M_ / 64, 512, 0, stream>>>(h1, W2T, b2, gamma, beta, out);
}

// Round 16
// 55.137 us; speedup vs baseline: 1.6368x; 1.6368x over previous
//
#include <hip/hip_runtime.h>
#include <hip/hip_bf16.h>

// TextEncoder: segment-mean pool -> relu(x@W1+b1) -> relu(h@W2+b2) -> LayerNorm
// R16: prep rebuilt (R15 probe: prep ~28us of the 55.9 total, ~2x its 16us
// traffic floor). (1) weight transpose now LDS-tiled: coalesced f32 reads,
// coalesced bf16 writes (was 557K scattered 4B loads, one 64B txn each).
// (2) pool: wave-per-word, 4 words/256-thr block (4096 blocks vs 16384).
// gemm1 (R11 BK=64) and gemm2_ln (R6) verbatim, single launches.
//
// Padding: W1T=[512][768] (rows>=500 zero) -> h1 pad cols = relu(0)=0;
// W2T=[320][512] (k>=500, n>=300 zero) -> pad out cols = 0, excluded from LN.

#define N_  64
#define L_  514
#define D_  768
#define W_  256
#define H1_ 500
#define H1P 512
#define H2_ 300
#define H2P 320
#define LN_EPS 1e-5f
#define M_  (N_ * W_)   // 16384

typedef __bf16 bf16x8 __attribute__((ext_vector_type(8)));
typedef float  f32x4  __attribute__((ext_vector_type(4)));

__device__ __forceinline__ void load_lds16(const void* g, void* l) {
    __builtin_amdgcn_global_load_lds(
        (const __attribute__((address_space(1))) void*)g,
        (__attribute__((address_space(3))) void*)l, 16, 0, 0);
}

__device__ __forceinline__ uint2 pack4(f32x4 v) {
    union { __hip_bfloat16 h[4]; uint2 u; } o;
    o.h[0] = __float2bfloat16(v[0]); o.h[1] = __float2bfloat16(v[1]);
    o.h[2] = __float2bfloat16(v[2]); o.h[3] = __float2bfloat16(v[3]);
    return o.u;
}

// ------------------------------------------------------------------ prep ---
// blocks [0, 4096): pooling, wave-per-word (4 words/block).
// blocks [4096, 4480): W1 -> W1T via 32x32 LDS tile transpose (24 kt x 16 nt).
// blocks [4480, 4640): W2 -> W2T via 32x32 LDS tile transpose (16 kt x 10 nt).
#define POOL_B (M_ / 4)            // 4096
#define CW1_B  (24 * 16)           // 384
#define CW2_B  (16 * 10)           // 160

__global__ __launch_bounds__(256) void prep_kernel(
    const float* __restrict__ texts, const int* __restrict__ wstart,
    const int* __restrict__ wend, const int* __restrict__ wlen,
    const float* __restrict__ W1, const float* __restrict__ W2,
    __hip_bfloat16* __restrict__ pooled, __hip_bfloat16* __restrict__ W1T,
    __hip_bfloat16* __restrict__ W2T)
{
    __shared__ float tile[32][33];
    int b = blockIdx.x;
    if (b < POOL_B) {
        const int wave = threadIdx.x >> 6, lane = threadIdx.x & 63;
        const int idx = b * 4 + wave;           // word id
        const int n = idx >> 8, w = idx & (W_ - 1);
        const int s = wstart[idx], e = wend[idx];   // wave-uniform
        const bool live = (w < wlen[n]);
        const float inv = live ? 1.0f / (float)max(e - s, 1) : 0.f;
        f32x4 a0 = {}, a1 = {}, a2 = {};
        if (live) {
            const float* base = texts + ((size_t)n * L_ + 1 + s) * D_ + lane * 4;
            for (int r = 0; r < e - s; ++r) {
                const float* p = base + (size_t)r * D_;
                a0 += *(const f32x4*)(p);
                a1 += *(const f32x4*)(p + 256);
                a2 += *(const f32x4*)(p + 512);
            }
            a0 *= inv; a1 *= inv; a2 *= inv;
        }
        __hip_bfloat16* dst = pooled + (size_t)idx * D_ + lane * 4;
        *(uint2*)(dst)       = pack4(a0);
        *(uint2*)(dst + 256) = pack4(a1);
        *(uint2*)(dst + 512) = pack4(a2);
    } else if (b < POOL_B + CW1_B) {
        // W1 [768 k][500 n] f32 -> W1T [512 n][768 k] bf16 (n>=500 -> 0)
        int t = b - POOL_B;
        int kt = t % 24, nt = t / 24;
        int r = threadIdx.x >> 5, c = threadIdx.x & 31;
        #pragma unroll
        for (int i = 0; i < 4; ++i) {
            int kk = kt * 32 + r + i * 8;       // 0..767
            int nn = nt * 32 + c;               // 0..511
            tile[r + i * 8][c] = (nn < H1_) ? W1[(size_t)kk * H1_ + nn] : 0.f;
        }
        __syncthreads();
        #pragma unroll
        for (int i = 0; i < 4; ++i) {
            int nn = nt * 32 + r + i * 8;
            int kk = kt * 32 + c;
            W1T[(size_t)nn * D_ + kk] = __float2bfloat16(tile[c][r + i * 8]);
        }
    } else {
        // W2 [512 k][300 n] f32 -> W2T [320 n][512 k] bf16 (n>=300|k>=500 -> 0)
        int t = b - POOL_B - CW1_B;
        int kt = t % 16, nt = t / 16;
        int r = threadIdx.x >> 5, c = threadIdx.x & 31;
        #pragma unroll
        for (int i = 0; i < 4; ++i) {
            int kk = kt * 32 + r + i * 8;       // 0..511
            int nn = nt * 32 + c;               // 0..319
            tile[r + i * 8][c] =
                (nn < H2_ && kk < H1_) ? W2[(size_t)kk * H2_ + nn] : 0.f;
        }
        __syncthreads();
        #pragma unroll
        for (int i = 0; i < 4; ++i) {
            int nn = nt * 32 + r + i * 8;
            int kk = kt * 32 + c;
            W2T[(size_t)nn * H1P + kk] = __float2bfloat16(tile[c][r + i * 8]);
        }
    }
}

// --------------------------------------------------------- GEMM1 (MFMA) ----
// [R11 verbatim] BM=256, BN=128, BK=64; 8 waves (4x2); 12 K-steps; 3 bufs x
// 48KB; depth-2 counted vmcnt (6 loads/wave/stage -> vmcnt(6), tail 0).
__global__ __launch_bounds__(512, 1) void gemm1_kernel(
    const ushort* __restrict__ A, const ushort* __restrict__ B,
    const float* __restrict__ b1, ushort* __restrict__ h1)
{
    constexpr int BUFB = 49152;                 // 384 rows * 128 B
    __shared__ __align__(16) char bufs[3 * BUFB];   // 144 KB
    const int tid  = threadIdx.x;
    const int wave = tid >> 6, lane = tid & 63;
    const int wm = wave >> 1, wn = wave & 1;    // 4 x 2
    const int t256 = (blockIdx.x & 7) * 32 + (blockIdx.x >> 3);
    const int bm = (t256 >> 2) * 256, bn = (t256 & 3) * 128;
    const int lrow8 = lane >> 3, lslot8 = lane & 7;
    const int g = lane >> 4, fr = lane & 15;

    f32x4 acc[4][4] = {};

    auto stage = [&](int buf, int kt) {
        char* base = bufs + buf * BUFB;
        #pragma unroll
        for (int c0 = 0; c0 < 6; ++c0) {
            int c = wave + c0 * 8;              // 0..47
            int row; const ushort* src;
            if (c < 32) { row = c * 8 + lrow8;        src = A + (size_t)(bm + row) * D_; }
            else        { row = (c - 32) * 8 + lrow8; src = B + (size_t)(bn + row) * D_; }
            int sslot = lslot8 ^ (row & 7);
            load_lds16(src + kt + sslot * 8, base + c * 1024);
        }
    };

    auto compute = [&](int t) {
        const char* base = bufs + (t % 3) * BUFB;
        #pragma unroll
        for (int h = 0; h < 2; ++h) {
            bf16x8 af[4], bf[4];
            #pragma unroll
            for (int mi = 0; mi < 4; ++mi) {
                int r = wm * 64 + mi * 16 + fr;
                af[mi] = *(const bf16x8*)(base + r * 128 + ((((h << 2) + g) ^ (r & 7)) << 4));
            }
            #pragma unroll
            for (int ni = 0; ni < 4; ++ni) {
                int r = wn * 64 + ni * 16 + fr;
                bf[ni] = *(const bf16x8*)(base + 32768 + r * 128 + ((((h << 2) + g) ^ (r & 7)) << 4));
            }
            __builtin_amdgcn_s_setprio(1);
            #pragma unroll
            for (int mi = 0; mi < 4; ++mi)
                #pragma unroll
                for (int ni = 0; ni < 4; ++ni)
                    acc[mi][ni] = __builtin_amdgcn_mfma_f32_16x16x32_bf16(
                        af[mi], bf[ni], acc[mi][ni], 0, 0, 0);
            __builtin_amdgcn_s_setprio(0);
        }
    };

    stage(0, 0); stage(1, 64);
    for (int t = 0; t < 11; ++t) {
        asm volatile("s_waitcnt vmcnt(6)" ::: "memory");   // stage t complete
        __builtin_amdgcn_s_barrier();
        if (t + 2 < 12) stage((t + 2) % 3, (t + 2) * 64);
        compute(t);
    }
    asm volatile("s_waitcnt vmcnt(0)" ::: "memory");
    __builtin_amdgcn_s_barrier();
    compute(11);

    #pragma unroll
    for (int mi = 0; mi < 4; ++mi)
        #pragma unroll
        for (int ni = 0; ni < 4; ++ni) {
            int col = bn + wn * 64 + ni * 16 + fr;
            float bv = (col < H1_) ? b1[col] : 0.f;
            #pragma unroll
            for (int j = 0; j < 4; ++j) {
                int row = bm + wm * 64 + mi * 16 + g * 4 + j;
                float v = acc[mi][ni][j] + bv;
                ((__hip_bfloat16*)h1)[(size_t)row * H1P + col] =
                    __float2bfloat16(v > 0.f ? v : 0.f);
            }
        }
}

// ------------------------------------------- GEMM2 + bias + relu + LN ------
// [R6 verbatim] BM=64, BN=320 full-row, K=512; 8 waves (2x4); 4-buf counted
// vmcnt (6/3/0); LN fused in epilogue.
__global__ __launch_bounds__(512, 1) void gemm2_ln_kernel(
    const ushort* __restrict__ A, const ushort* __restrict__ B,
    const float* __restrict__ b2, const float* __restrict__ gamma,
    const float* __restrict__ beta, float* __restrict__ out)
{
    constexpr int BUFB = 24576;                 // (64+320) rows * 64 B
    __shared__ __align__(16) char bufs[4 * BUFB];   // 96 KB
    __shared__ float red[2][32][4][2];          // [wm][row][wn][sum|sq]
    const int tid  = threadIdx.x;
    const int wave = tid >> 6, lane = tid & 63;
    const int wm = wave >> 2, wn = wave & 3;    // 2 x 4
    const int bm = blockIdx.x * 64;
    const int lrow = lane >> 2, lslot = lane & 3;
    const int g = lane >> 4, fr = lane & 15;

    f32x4 acc[2][5] = {};

    auto stage = [&](int buf, int kt) {
        char* base = bufs + buf * BUFB;
        #pragma unroll
        for (int c0 = 0; c0 < 3; ++c0) {
            int c = wave + c0 * 8;              // 0..23
            int row; const ushort* src;
            if (c < 4) { row = c * 16 + lrow; src = A + (size_t)(bm + row) * H1P; }
            else       { row = (c - 4) * 16 + lrow; src = B + (size_t)row * H1P; }
            int sslot = lslot ^ ((row >> 1) & 3);
            load_lds16(src + kt + sslot * 8, base + c * 1024);
        }
    };

    auto compute = [&](int t) {
        const char* base = bufs + (t & 3) * BUFB;
        bf16x8 af[2], bf[5];
        #pragma unroll
        for (int mi = 0; mi < 2; ++mi) {
            int r = wm * 32 + mi * 16 + fr;
            af[mi] = *(const bf16x8*)(base + r * 64 + ((g ^ ((r >> 1) & 3)) << 4));
        }
        #pragma unroll
        for (int ni = 0; ni < 5; ++ni) {
            int r = wn * 80 + ni * 16 + fr;
            bf[ni] = *(const bf16x8*)(base + 4096 + r * 64 + ((g ^ ((r >> 1) & 3)) << 4));
        }
        __builtin_amdgcn_s_setprio(1);
        #pragma unroll
        for (int mi = 0; mi < 2; ++mi)
            #pragma unroll
            for (int ni = 0; ni < 5; ++ni)
                acc[mi][ni] = __builtin_amdgcn_mfma_f32_16x16x32_bf16(
                    af[mi], bf[ni], acc[mi][ni], 0, 0, 0);
        __builtin_amdgcn_s_setprio(0);
    };

    stage(0, 0); stage(1, 32); stage(2, 64);
    for (int t = 0; t < 14; ++t) {
        asm volatile("s_waitcnt vmcnt(6)" ::: "memory");
        __builtin_amdgcn_s_barrier();
        if (t + 3 < 16) stage((t + 3) & 3, (t + 3) * 32);
        compute(t);
    }
    asm volatile("s_waitcnt vmcnt(3)" ::: "memory");
    __builtin_amdgcn_s_barrier();
    compute(14);
    asm volatile("s_waitcnt vmcnt(0)" ::: "memory");
    __builtin_amdgcn_s_barrier();
    compute(15);

    float vals[2][5][4];
    float rsum[2][4] = {}, rsq[2][4] = {};
    #pragma unroll
    for (int ni = 0; ni < 5; ++ni) {
        int col = wn * 80 + ni * 16 + fr;
        float bv = (col < H2_) ? b2[col] : 0.f;
        #pragma unroll
        for (int mi = 0; mi < 2; ++mi)
            #pragma unroll
            for (int j = 0; j < 4; ++j) {
                float v = acc[mi][ni][j] + bv;
                v = v > 0.f ? v : 0.f;
                vals[mi][ni][j] = v;
                rsum[mi][j] += v;
                rsq[mi][j]  += v * v;
            }
    }
    #pragma unroll
    for (int off = 1; off < 16; off <<= 1)
        #pragma unroll
        for (int mi = 0; mi < 2; ++mi)
            #pragma unroll
            for (int j = 0; j < 4; ++j) {
                rsum[mi][j] += __shfl_xor(rsum[mi][j], off);
                rsq[mi][j]  += __shfl_xor(rsq[mi][j], off);
            }
    if (fr == 0) {
        #pragma unroll
        for (int mi = 0; mi < 2; ++mi)
            #pragma unroll
            for (int j = 0; j < 4; ++j) {
                int r32 = mi * 16 + g * 4 + j;
                red[wm][r32][wn][0] = rsum[mi][j];
                red[wm][r32][wn][1] = rsq[mi][j];
            }
    }
    __syncthreads();
    #pragma unroll
    for (int mi = 0; mi < 2; ++mi) {
        #pragma unroll
        for (int j = 0; j < 4; ++j) {
            int r32 = mi * 16 + g * 4 + j;
            float S  = red[wm][r32][0][0] + red[wm][r32][1][0]
                     + red[wm][r32][2][0] + red[wm][r32][3][0];
            float SQ = red[wm][r32][0][1] + red[wm][r32][1][1]
                     + red[wm][r32][2][1] + red[wm][r32][3][1];
            float mu   = S * (1.0f / H2_);
            float var  = SQ * (1.0f / H2_) - mu * mu;
            float rstd = rsqrtf(var + LN_EPS);
            int row = bm + wm * 32 + r32;
            #pragma unroll
            for (int ni = 0; ni < 5; ++ni) {
                int col = wn * 80 + ni * 16 + fr;
                if (col < H2_)
                    out[(size_t)row * H2_ + col] =
                        (vals[mi][ni][j] - mu) * rstd * gamma[col] + beta[col];
            }
        }
    }
}

// ----------------------------------------------------------------- launch ---
extern "C" void kernel_launch(void* const* d_in, const int* in_sizes, int n_in,
                              void* d_out, int out_size, void* d_ws, size_t ws_size,
                              hipStream_t stream)
{
    const float* texts  = (const float*)d_in[0];
    const int*   wstart = (const int*)  d_in[1];
    const int*   wend   = (const int*)  d_in[2];
    const int*   wlen   = (const int*)  d_in[3];
    const float* W1     = (const float*)d_in[4];
    const float* b1     = (const float*)d_in[5];
    const float* W2     = (const float*)d_in[6];
    const float* b2     = (const float*)d_in[7];
    const float* gamma  = (const float*)d_in[8];
    const float* beta   = (const float*)d_in[9];
    float* out = (float*)d_out;

    ushort* pooled = (ushort*)d_ws;                 // M x 768 bf16
    ushort* h1     = pooled + (size_t)M_ * D_;      // M x 512 bf16
    ushort* W1T    = h1 + (size_t)M_ * H1P;         // 512 x 768 bf16
    ushort* W2T    = W1T + (size_t)H1P * D_;        // 320 x 512 bf16

    prep_kernel<<<POOL_B + CW1_B + CW2_B, 256, 0, stream>>>(
        texts, wstart, wend, wlen, W1, W2,
        (__hip_bfloat16*)pooled, (__hip_bfloat16*)W1T, (__hip_bfloat16*)W2T);

    gemm1_kernel<<<256, 512, 0, stream>>>(pooled, W1T, b1, h1);

    gemm2_ln_kernel<<<M_ / 64, 512, 0, stream>>>(h1, W2T, b2, gamma, beta, out);
}